// Round 1
// baseline (2341.676 us; speedup 1.0000x reference)
//
#include <hip/hip_runtime.h>
#include <hip/hip_bf16.h>
#include <float.h>

typedef _Float16 f16x8 __attribute__((ext_vector_type(8)));
typedef float f32x4 __attribute__((ext_vector_type(4)));

#define GRAPHS 64
#define NPG 2048
#define DIM 128
#define NNODES (GRAPHS * NPG)
#define NEDGES (NNODES * 16)

// ---------------- embed: x[i] = emb[node_ids[i]] ----------------
__global__ __launch_bounds__(256) void embed_kernel(const int* __restrict__ ids,
    const float* __restrict__ emb, float* __restrict__ x) {
  int idx = blockIdx.x * 256 + threadIdx.x;
  int nd = idx >> 5, part = idx & 31;
  int id = ids[nd];
  *(float4*)(x + (size_t)nd * 128 + part * 4) =
      *(const float4*)(emb + (size_t)id * 128 + part * 4);
}

// ---------------- CSR build ----------------
__global__ __launch_bounds__(256) void count_kernel(const int* __restrict__ dst,
    const int* __restrict__ em, int* __restrict__ cnt, int E) {
  int e = blockIdx.x * 256 + threadIdx.x;
  if (e >= E) return;
  if (em && !em[e]) return;
  atomicAdd(&cnt[dst[e]], 1);
}

__global__ __launch_bounds__(1024) void scanA(const int* __restrict__ cnt, int* __restrict__ off,
    int* __restrict__ bsum, int nscan, int ncnt) {
  __shared__ int tmp[1024];
  int i = blockIdx.x * 1024 + threadIdx.x;
  int v = (i < ncnt) ? cnt[i] : 0;
  tmp[threadIdx.x] = v;
  for (int s = 1; s < 1024; s <<= 1) {
    __syncthreads();
    int t = ((int)threadIdx.x >= s) ? tmp[threadIdx.x - s] : 0;
    __syncthreads();
    tmp[threadIdx.x] += t;
  }
  __syncthreads();
  if (i < nscan) off[i] = tmp[threadIdx.x] - v;  // exclusive
  if (threadIdx.x == 1023) bsum[blockIdx.x] = tmp[1023];
}

__global__ void scanB(int* bsum, int nb) {
  if (threadIdx.x == 0 && blockIdx.x == 0) {
    int acc = 0;
    for (int i = 0; i < nb; ++i) { int t = bsum[i]; bsum[i] = acc; acc += t; }
  }
}

__global__ __launch_bounds__(1024) void scanC(int* __restrict__ off, const int* __restrict__ bsum,
    int* __restrict__ cur, int nscan, int ncnt) {
  int i = blockIdx.x * 1024 + threadIdx.x;
  if (i >= nscan) return;
  int v = off[i] + bsum[blockIdx.x];
  off[i] = v;
  if (i < ncnt) cur[i] = v;
}

__global__ __launch_bounds__(256) void fill_kernel(const int* __restrict__ src,
    const int* __restrict__ dst, const int* __restrict__ em, int* __restrict__ cur,
    int* __restrict__ esort, int E) {
  int e = blockIdx.x * 256 + threadIdx.x;
  if (e >= E) return;
  if (em && !em[e]) return;
  int p = atomicAdd(&cur[dst[e]], 1);
  esort[p] = src[e];
}

// ---------------- aggregate: mean over incoming edges ----------------
__global__ __launch_bounds__(256) void aggregate_kernel(const float* __restrict__ x,
    const int* __restrict__ off, const int* __restrict__ esrc, float* __restrict__ mean, int n) {
  int w = blockIdx.x * 4 + (threadIdx.x >> 6);
  int lane = threadIdx.x & 63;
  if (w >= n) return;
  int b = off[w], e = off[w + 1];
  float sx = 0.f, sy = 0.f;
  for (int i = b; i < e; ++i) {
    int srcn = esrc[i];
    float2 v = *(const float2*)(x + (size_t)srcn * 128 + lane * 2);
    sx += v.x; sy += v.y;
  }
  int c = e - b;
  float inv = 1.f / (float)(c > 0 ? c : 1);
  float2 o; o.x = sx * inv; o.y = sy * inv;
  *(float2*)(mean + (size_t)w * 128 + lane * 2) = o;
}

// ---------------- fused SAGE transform: OUT = relu(mean@WlT + bl + x@WrT) ----------------
// OUT may alias MEANIN (each block/wave reads its own rows before writing them).
__global__ __launch_bounds__(256) void sage_gemm(const float* __restrict__ X,
    const float* MEANIN, float* OUT,
    const float* __restrict__ Wl, const float* __restrict__ Wr, const float* __restrict__ bl) {
  __shared__ _Float16 WB[8][8][64][8];  // [ks][nf][lane][8] = 64KB
  int tid = threadIdx.x;
  for (int q = tid; q < 4096; q += 256) {
    int ks = q >> 9, nf = (q >> 6) & 7, l = q & 63;
    int ncol = nf * 16 + (l & 15);
    int k0 = (ks & 3) * 32 + ((l >> 4) << 3);
    const float* wsrc = ((ks < 4) ? Wl : Wr) + ncol * 128 + k0;  // B[k][n] = W[n][k]
    f16x8 w;
#pragma unroll
    for (int j = 0; j < 8; ++j) w[j] = (_Float16)wsrc[j];
    *(f16x8*)(&WB[ks][nf][l][0]) = w;
  }
  __syncthreads();
  int wave = tid >> 6, lane = tid & 63;
  int r0 = blockIdx.x * 64 + wave * 16;
  int row = r0 + (lane & 15);
  int kb = (lane >> 4) << 3;
  f32x4 acc[8];
#pragma unroll
  for (int nf = 0; nf < 8; ++nf) acc[nf] = (f32x4){0.f, 0.f, 0.f, 0.f};
#pragma unroll
  for (int ks = 0; ks < 8; ++ks) {
    const float* A = (ks < 4) ? MEANIN : X;
    const float* ap = A + (size_t)row * 128 + (ks & 3) * 32 + kb;
    f16x8 a;
#pragma unroll
    for (int j = 0; j < 8; ++j) a[j] = (_Float16)ap[j];
#pragma unroll
    for (int nf = 0; nf < 8; ++nf) {
      f16x8 b = *(const f16x8*)(&WB[ks][nf][lane][0]);
      acc[nf] = __builtin_amdgcn_mfma_f32_16x16x32_f16(a, b, acc[nf], 0, 0, 0);
    }
  }
  int rbase = r0 + ((lane >> 4) << 2);
#pragma unroll
  for (int nf = 0; nf < 8; ++nf) {
    int col = nf * 16 + (lane & 15);
    float bias = bl[col];
#pragma unroll
    for (int r = 0; r < 4; ++r) {
      float v = acc[nf][r] + bias;
      OUT[(size_t)(rbase + r) * 128 + col] = fmaxf(v, 0.f);
    }
  }
}

// ---------------- score = tanh(x.pw / ||pw||) ----------------
__global__ __launch_bounds__(256) void score_kernel(const float* __restrict__ x,
    const float* __restrict__ pw, float* __restrict__ sc, int n) {
  int w = blockIdx.x * 4 + (threadIdx.x >> 6);
  int lane = threadIdx.x & 63;
  if (w >= n) return;
  float2 xv = *(const float2*)(x + (size_t)w * 128 + lane * 2);
  float2 wv = *(const float2*)(pw + lane * 2);
  float d = xv.x * wv.x + xv.y * wv.y;
  float q = wv.x * wv.x + wv.y * wv.y;
  for (int o = 32; o > 0; o >>= 1) { d += __shfl_xor(d, o); q += __shfl_xor(q, o); }
  if (lane == 0) sc[w] = tanhf(d / sqrtf(q));
}

// ---------------- per-graph top-k via bitonic sort (desc) ----------------
__global__ __launch_bounds__(256) void topk_kernel(const float* __restrict__ sc, int n_per, int k,
    float* __restrict__ ts, int* __restrict__ perm, int* __restrict__ noo) {
  __shared__ float s[2048];
  __shared__ int si[2048];
  int g = blockIdx.x, tid = threadIdx.x;
  for (int i = tid; i < 2048; i += 256) {
    bool val = (i < n_per);
    s[i] = val ? sc[g * n_per + i] : -FLT_MAX;
    si[i] = i;
    if (val) noo[g * n_per + i] = -1;
  }
  __syncthreads();
  for (int kk = 2; kk <= 2048; kk <<= 1) {
    for (int j = kk >> 1; j > 0; j >>= 1) {
      for (int i = tid; i < 2048; i += 256) {
        int l = i ^ j;
        if (l > i) {
          float a = s[i], b = s[l];
          bool descBlock = ((i & kk) == 0);
          bool dosw = descBlock ? (a < b) : (a > b);
          if (dosw) { s[i] = b; s[l] = a; int t = si[i]; si[i] = si[l]; si[l] = t; }
        }
      }
      __syncthreads();
    }
  }
  for (int r = tid; r < k; r += 256) {
    int og = g * n_per + si[r];
    int ng = g * k + r;
    ts[ng] = s[r];
    perm[ng] = og;
    noo[og] = ng;
  }
}

// ---------------- gather + scale: xnew[v] = xold[perm[v]] * ts[v] ----------------
__global__ __launch_bounds__(256) void gather_kernel(const float* __restrict__ xold,
    const int* __restrict__ perm, const float* __restrict__ ts, float* __restrict__ xnew, int n_new) {
  int idx = blockIdx.x * 256 + threadIdx.x;
  int v = idx >> 5, part = idx & 31;
  if (v >= n_new) return;
  float t = ts[v];
  float4 val = *(const float4*)(xold + (size_t)perm[v] * 128 + part * 4);
  val.x *= t; val.y *= t; val.z *= t; val.w *= t;
  *(float4*)(xnew + (size_t)v * 128 + part * 4) = val;
}

// ---------------- readout: h[g] += [max, mean] ----------------
__global__ __launch_bounds__(128) void readout_kernel(const float* __restrict__ x, int k,
    float* __restrict__ h) {
  int g = blockIdx.x, d = threadIdx.x;
  const float* p = x + (size_t)g * k * 128 + d;
  float vmax = -FLT_MAX, vs = 0.f;
  for (int i = 0; i < k; ++i) {
    float v = p[(size_t)i * 128];
    vmax = fmaxf(vmax, v);
    vs += v;
  }
  h[g * 256 + d] += vmax;
  h[g * 256 + 128 + d] += vs / (float)k;
}

// ---------------- edge remap after pooling ----------------
__global__ __launch_bounds__(256) void remap_kernel(const int* __restrict__ src_in,
    const int* __restrict__ dst_in, const int* __restrict__ em_in, const int* __restrict__ noo,
    int* __restrict__ src_out, int* __restrict__ dst_out, int* __restrict__ em_out, int E) {
  int e = blockIdx.x * 256 + threadIdx.x;
  if (e >= E) return;
  int ok = (em_in == nullptr) ? 1 : em_in[e];
  int s = 0, d = 0;
  if (ok) {
    s = noo[src_in[e]];
    d = noo[dst_in[e]];
    ok = (s >= 0) && (d >= 0);
  }
  src_out[e] = ok ? s : 0;
  dst_out[e] = ok ? d : 0;
  em_out[e] = ok ? 1 : 0;
}

// ---------------- final MLP ----------------
__global__ __launch_bounds__(256) void mlp1(const float* __restrict__ h, const float* __restrict__ W1,
    const float* __restrict__ b1, float* __restrict__ h1) {
  int o = blockIdx.x * 256 + threadIdx.x;  // 64*128
  int g = o >> 7, j = o & 127;
  const float* hp = h + g * 256;
  const float* wp = W1 + j * 256;
  float a = b1[j];
  for (int c = 0; c < 256; ++c) a += hp[c] * wp[c];
  h1[o] = fmaxf(a, 0.f);
}

__global__ __launch_bounds__(256) void mlp2(const float* __restrict__ h1, const float* __restrict__ W2,
    const float* __restrict__ b2, float* __restrict__ h2) {
  int o = blockIdx.x * 256 + threadIdx.x;  // 64*64
  int g = o >> 6, j = o & 63;
  const float* hp = h1 + g * 128;
  const float* wp = W2 + j * 128;
  float a = b2[j];
  for (int c = 0; c < 128; ++c) a += hp[c] * wp[c];
  h2[o] = fmaxf(a, 0.f);
}

__global__ __launch_bounds__(64) void mlp3(const float* __restrict__ h2, const float* __restrict__ W3,
    const float* __restrict__ b3, float* __restrict__ out) {
  int g = threadIdx.x;
  if (g >= 64) return;
  const float* hp = h2 + g * 64;
  float a = b3[0];
  for (int c = 0; c < 64; ++c) a += hp[c] * W3[c];
  out[g] = 1.f / (1.f + expf(-a));
}

extern "C" void kernel_launch(void* const* d_in, const int* in_sizes, int n_in,
                              void* d_out, int out_size, void* d_ws, size_t ws_size,
                              hipStream_t stream) {
  const int* node_ids = (const int*)d_in[0];
  const int* ei = (const int*)d_in[1];
  const float* emb = (const float*)d_in[3];
  const float* W[3][4] = {
      {(const float*)d_in[4], (const float*)d_in[5], (const float*)d_in[6], (const float*)d_in[7]},
      {(const float*)d_in[8], (const float*)d_in[9], (const float*)d_in[10], (const float*)d_in[11]},
      {(const float*)d_in[12], (const float*)d_in[13], (const float*)d_in[14], (const float*)d_in[15]}};
  const float* W1 = (const float*)d_in[16];
  const float* b1 = (const float*)d_in[17];
  const float* W2 = (const float*)d_in[18];
  const float* b2 = (const float*)d_in[19];
  const float* W3 = (const float*)d_in[20];
  const float* b3 = (const float*)d_in[21];
  float* out = (float*)d_out;

  const int E = NEDGES;
  char* ws = (char*)d_ws;
  size_t o = 0;
  auto alloc = [&](size_t bytes) { void* p = ws + o; o = (o + bytes + 255) & ~(size_t)255; return p; };
  float* X = (float*)alloc((size_t)NNODES * 128 * 4);
  float* MEAN = (float*)alloc((size_t)NNODES * 128 * 4);
  int* ES = (int*)alloc((size_t)E * 4);
  int* ED = (int*)alloc((size_t)E * 4);
  int* EM = (int*)alloc((size_t)E * 4);
  int* ESORT = (int*)alloc((size_t)E * 4);
  int* OFF = (int*)alloc((size_t)(NNODES + 1) * 4);
  int* CUR = (int*)alloc((size_t)NNODES * 4);
  int* CNT = (int*)alloc((size_t)NNODES * 4);
  int* BSUM = (int*)alloc(1024);
  float* SC = (float*)alloc((size_t)NNODES * 4);
  float* TS = (float*)alloc((size_t)NNODES * 4);
  int* PERM = (int*)alloc((size_t)NNODES * 4);
  int* NOO = (int*)alloc((size_t)NNODES * 4);
  float* H = (float*)alloc(64 * 256 * 4);
  float* H1 = (float*)alloc(64 * 128 * 4);
  float* H2 = (float*)alloc(64 * 64 * 4);

  embed_kernel<<<NNODES * 32 / 256, 256, 0, stream>>>(node_ids, emb, X);
  hipMemsetAsync(H, 0, 64 * 256 * 4, stream);

  struct LayerP { int n, np, k; };
  LayerP L[3] = {{131072, 2048, 1639}, {104896, 1639, 1312}, {83968, 1312, 1050}};
  const int* src = ei;
  const int* dst = ei + E;
  const int* em = nullptr;

  for (int li = 0; li < 3; ++li) {
    int n = L[li].n, np = L[li].np, k = L[li].k;
    int n_new = 64 * k;
    const float *Wl = W[li][0], *Wr = W[li][1], *bl = W[li][2], *pw = W[li][3];

    hipMemsetAsync(CNT, 0, (size_t)n * 4, stream);
    count_kernel<<<E / 256, 256, 0, stream>>>(dst, em, CNT, E);
    int nscan = n + 1, nblk = (nscan + 1023) / 1024;
    scanA<<<nblk, 1024, 0, stream>>>(CNT, OFF, BSUM, nscan, n);
    scanB<<<1, 64, 0, stream>>>(BSUM, nblk);
    scanC<<<nblk, 1024, 0, stream>>>(OFF, BSUM, CUR, nscan, n);
    fill_kernel<<<E / 256, 256, 0, stream>>>(src, dst, em, CUR, ESORT, E);
    aggregate_kernel<<<n / 4, 256, 0, stream>>>(X, OFF, ESORT, MEAN, n);
    sage_gemm<<<n / 64, 256, 0, stream>>>(X, MEAN, MEAN, Wl, Wr, bl);
    score_kernel<<<n / 4, 256, 0, stream>>>(MEAN, pw, SC, n);
    topk_kernel<<<GRAPHS, 256, 0, stream>>>(SC, np, k, TS, PERM, NOO);
    gather_kernel<<<n_new / 8, 256, 0, stream>>>(MEAN, PERM, TS, X, n_new);
    readout_kernel<<<GRAPHS, 128, 0, stream>>>(X, k, H);
    if (li < 2) {
      remap_kernel<<<E / 256, 256, 0, stream>>>(src, dst, em, NOO, ES, ED, EM, E);
      src = ES; dst = ED; em = EM;
    }
  }

  mlp1<<<32, 256, 0, stream>>>(H, W1, b1, H1);
  mlp2<<<16, 256, 0, stream>>>(H1, W2, b2, H2);
  mlp3<<<1, 64, 0, stream>>>(H2, W3, b3, out);
}

// Round 2
// 1380.030 us; speedup vs baseline: 1.6968x; 1.6968x over previous
//
#include <hip/hip_runtime.h>
#include <hip/hip_bf16.h>
#include <float.h>

typedef _Float16 f16x8 __attribute__((ext_vector_type(8)));
typedef float f32x4 __attribute__((ext_vector_type(4)));

#define GRAPHS 64
#define NPG 2048
#define DIM 128
#define NNODES (GRAPHS * NPG)
#define NEDGES (NNODES * 16)
#define RSLICES 16

// ---------------- embed: x[i] = emb[node_ids[i]] ----------------
__global__ __launch_bounds__(256) void embed_kernel(const int* __restrict__ ids,
    const float* __restrict__ emb, float* __restrict__ x) {
  int idx = blockIdx.x * 256 + threadIdx.x;
  int nd = idx >> 5, part = idx & 31;
  int id = ids[nd];
  *(float4*)(x + (size_t)nd * 128 + part * 4) =
      *(const float4*)(emb + (size_t)id * 128 + part * 4);
}

// ---------------- CSR build ----------------
__global__ __launch_bounds__(256) void count_kernel(const int* __restrict__ dst,
    const int* __restrict__ em, int* __restrict__ cnt, int E) {
  int e = blockIdx.x * 256 + threadIdx.x;
  if (e >= E) return;
  if (em && !em[e]) return;
  atomicAdd(&cnt[dst[e]], 1);
}

__global__ __launch_bounds__(1024) void scanA(const int* __restrict__ cnt, int* __restrict__ off,
    int* __restrict__ bsum, int nscan, int ncnt) {
  __shared__ int tmp[1024];
  int i = blockIdx.x * 1024 + threadIdx.x;
  int v = (i < ncnt) ? cnt[i] : 0;
  tmp[threadIdx.x] = v;
  for (int s = 1; s < 1024; s <<= 1) {
    __syncthreads();
    int t = ((int)threadIdx.x >= s) ? tmp[threadIdx.x - s] : 0;
    __syncthreads();
    tmp[threadIdx.x] += t;
  }
  __syncthreads();
  if (i < nscan) off[i] = tmp[threadIdx.x] - v;  // exclusive
  if (threadIdx.x == 1023) bsum[blockIdx.x] = tmp[1023];
}

__global__ void scanB(int* bsum, int nb) {
  if (threadIdx.x == 0 && blockIdx.x == 0) {
    int acc = 0;
    for (int i = 0; i < nb; ++i) { int t = bsum[i]; bsum[i] = acc; acc += t; }
  }
}

__global__ __launch_bounds__(1024) void scanC(int* __restrict__ off, const int* __restrict__ bsum,
    int* __restrict__ cur, int nscan, int ncnt) {
  int i = blockIdx.x * 1024 + threadIdx.x;
  if (i >= nscan) return;
  int v = off[i] + bsum[blockIdx.x];
  off[i] = v;
  if (i < ncnt) cur[i] = v;
}

__global__ __launch_bounds__(256) void fill_kernel(const int* __restrict__ src,
    const int* __restrict__ dst, const int* __restrict__ em, int* __restrict__ cur,
    int* __restrict__ esort, int E) {
  int e = blockIdx.x * 256 + threadIdx.x;
  if (e >= E) return;
  if (em && !em[e]) return;
  int p = atomicAdd(&cur[dst[e]], 1);
  esort[p] = src[e];
}

// ---------------- aggregate: mean over incoming edges ----------------
__global__ __launch_bounds__(256) void aggregate_kernel(const float* __restrict__ x,
    const int* __restrict__ off, const int* __restrict__ esrc, float* __restrict__ mean, int n) {
  int w = blockIdx.x * 4 + (threadIdx.x >> 6);
  int lane = threadIdx.x & 63;
  if (w >= n) return;
  int b = off[w], e = off[w + 1];
  float sx = 0.f, sy = 0.f;
  for (int i = b; i < e; ++i) {
    int srcn = esrc[i];
    float2 v = *(const float2*)(x + (size_t)srcn * 128 + lane * 2);
    sx += v.x; sy += v.y;
  }
  int c = e - b;
  float inv = 1.f / (float)(c > 0 ? c : 1);
  float2 o; o.x = sx * inv; o.y = sy * inv;
  *(float2*)(mean + (size_t)w * 128 + lane * 2) = o;
}

// ---------------- fused SAGE transform: OUT = relu(mean@WlT + bl + x@WrT) ----------------
__global__ __launch_bounds__(256) void sage_gemm(const float* __restrict__ X,
    const float* MEANIN, float* OUT,
    const float* __restrict__ Wl, const float* __restrict__ Wr, const float* __restrict__ bl) {
  __shared__ _Float16 WB[8][8][64][8];  // [ks][nf][lane][8] = 64KB
  int tid = threadIdx.x;
  for (int q = tid; q < 4096; q += 256) {
    int ks = q >> 9, nf = (q >> 6) & 7, l = q & 63;
    int ncol = nf * 16 + (l & 15);
    int k0 = (ks & 3) * 32 + ((l >> 4) << 3);
    const float* wsrc = ((ks < 4) ? Wl : Wr) + ncol * 128 + k0;  // B[k][n] = W[n][k]
    f16x8 w;
#pragma unroll
    for (int j = 0; j < 8; ++j) w[j] = (_Float16)wsrc[j];
    *(f16x8*)(&WB[ks][nf][l][0]) = w;
  }
  __syncthreads();
  int wave = tid >> 6, lane = tid & 63;
  int r0 = blockIdx.x * 64 + wave * 16;
  int row = r0 + (lane & 15);
  int kb = (lane >> 4) << 3;
  f32x4 acc[8];
#pragma unroll
  for (int nf = 0; nf < 8; ++nf) acc[nf] = (f32x4){0.f, 0.f, 0.f, 0.f};
#pragma unroll
  for (int ks = 0; ks < 8; ++ks) {
    const float* A = (ks < 4) ? MEANIN : X;
    const float* ap = A + (size_t)row * 128 + (ks & 3) * 32 + kb;
    f16x8 a;
#pragma unroll
    for (int j = 0; j < 8; ++j) a[j] = (_Float16)ap[j];
#pragma unroll
    for (int nf = 0; nf < 8; ++nf) {
      f16x8 b = *(const f16x8*)(&WB[ks][nf][lane][0]);
      acc[nf] = __builtin_amdgcn_mfma_f32_16x16x32_f16(a, b, acc[nf], 0, 0, 0);
    }
  }
  int rbase = r0 + ((lane >> 4) << 2);
#pragma unroll
  for (int nf = 0; nf < 8; ++nf) {
    int col = nf * 16 + (lane & 15);
    float bias = bl[col];
#pragma unroll
    for (int r = 0; r < 4; ++r) {
      float v = acc[nf][r] + bias;
      OUT[(size_t)(rbase + r) * 128 + col] = fmaxf(v, 0.f);
    }
  }
}

// ---------------- score = tanh(x.pw / ||pw||) ----------------
__global__ __launch_bounds__(256) void score_kernel(const float* __restrict__ x,
    const float* __restrict__ pw, float* __restrict__ sc, int n) {
  int w = blockIdx.x * 4 + (threadIdx.x >> 6);
  int lane = threadIdx.x & 63;
  if (w >= n) return;
  float2 xv = *(const float2*)(x + (size_t)w * 128 + lane * 2);
  float2 wv = *(const float2*)(pw + lane * 2);
  float d = xv.x * wv.x + xv.y * wv.y;
  float q = wv.x * wv.x + wv.y * wv.y;
  for (int o = 32; o > 0; o >>= 1) { d += __shfl_xor(d, o); q += __shfl_xor(q, o); }
  if (lane == 0) sc[w] = tanhf(d / sqrtf(q));
}

// ---------------- per-graph top-k via bitonic sort (desc) ----------------
__global__ __launch_bounds__(256) void topk_kernel(const float* __restrict__ sc, int n_per, int k,
    float* __restrict__ ts, int* __restrict__ perm, int* __restrict__ noo) {
  __shared__ float s[2048];
  __shared__ int si[2048];
  int g = blockIdx.x, tid = threadIdx.x;
  for (int i = tid; i < 2048; i += 256) {
    bool val = (i < n_per);
    s[i] = val ? sc[g * n_per + i] : -FLT_MAX;
    si[i] = i;
    if (val) noo[g * n_per + i] = -1;
  }
  __syncthreads();
  for (int kk = 2; kk <= 2048; kk <<= 1) {
    for (int j = kk >> 1; j > 0; j >>= 1) {
      for (int i = tid; i < 2048; i += 256) {
        int l = i ^ j;
        if (l > i) {
          float a = s[i], b = s[l];
          bool descBlock = ((i & kk) == 0);
          bool dosw = descBlock ? (a < b) : (a > b);
          if (dosw) { s[i] = b; s[l] = a; int t = si[i]; si[i] = si[l]; si[l] = t; }
        }
      }
      __syncthreads();
    }
  }
  for (int r = tid; r < k; r += 256) {
    int og = g * n_per + si[r];
    int ng = g * k + r;
    ts[ng] = s[r];
    perm[ng] = og;
    noo[og] = ng;
  }
}

// ---------------- gather + scale: xnew[v] = xold[perm[v]] * ts[v] ----------------
__global__ __launch_bounds__(256) void gather_kernel(const float* __restrict__ xold,
    const int* __restrict__ perm, const float* __restrict__ ts, float* __restrict__ xnew, int n_new) {
  int idx = blockIdx.x * 256 + threadIdx.x;
  int v = idx >> 5, part = idx & 31;
  if (v >= n_new) return;
  float t = ts[v];
  float4 val = *(const float4*)(xold + (size_t)perm[v] * 128 + part * 4);
  val.x *= t; val.y *= t; val.z *= t; val.w *= t;
  *(float4*)(xnew + (size_t)v * 128 + part * 4) = val;
}

// ---------------- readout stage 1: per-(graph,slice) partial max/sum ----------------
__global__ __launch_bounds__(256) void readout_part(const float* __restrict__ x, int k,
    float* __restrict__ pmax, float* __restrict__ psum) {
  int g = blockIdx.x >> 4;           // / RSLICES
  int slice = blockIdx.x & (RSLICES - 1);
  int d = threadIdx.x & 127;
  int half = threadIdx.x >> 7;       // 0 or 1
  int rpb = (k + RSLICES - 1) / RSLICES;
  int r0 = slice * rpb;
  int r1 = r0 + rpb; if (r1 > k) r1 = k;
  float vmax = -FLT_MAX, vs = 0.f;
  for (int r = r0 + half; r < r1; r += 2) {
    float v = x[((size_t)g * k + r) * 128 + d];
    vmax = fmaxf(vmax, v);
    vs += v;
  }
  __shared__ float smax[256], ssum[256];
  smax[threadIdx.x] = vmax;
  ssum[threadIdx.x] = vs;
  __syncthreads();
  if (threadIdx.x < 128) {
    vmax = fmaxf(smax[threadIdx.x], smax[threadIdx.x + 128]);
    vs = ssum[threadIdx.x] + ssum[threadIdx.x + 128];
    pmax[(size_t)(g * RSLICES + slice) * 128 + d] = vmax;
    psum[(size_t)(g * RSLICES + slice) * 128 + d] = vs;
  }
}

// ---------------- readout stage 2: combine slices, h[g] += [max, mean] ----------------
__global__ __launch_bounds__(256) void readout_comb(const float* __restrict__ pmax,
    const float* __restrict__ psum, int k, float* __restrict__ h) {
  int idx = blockIdx.x * 256 + threadIdx.x;  // 64*128
  int g = idx >> 7, d = idx & 127;
  float vmax = -FLT_MAX, vs = 0.f;
#pragma unroll
  for (int s = 0; s < RSLICES; ++s) {
    vmax = fmaxf(vmax, pmax[(size_t)(g * RSLICES + s) * 128 + d]);
    vs += psum[(size_t)(g * RSLICES + s) * 128 + d];
  }
  h[g * 256 + d] += vmax;
  h[g * 256 + 128 + d] += vs / (float)k;
}

// ---------------- edge remap after pooling ----------------
__global__ __launch_bounds__(256) void remap_kernel(const int* __restrict__ src_in,
    const int* __restrict__ dst_in, const int* __restrict__ em_in, const int* __restrict__ noo,
    int* __restrict__ src_out, int* __restrict__ dst_out, int* __restrict__ em_out, int E) {
  int e = blockIdx.x * 256 + threadIdx.x;
  if (e >= E) return;
  int ok = (em_in == nullptr) ? 1 : em_in[e];
  int s = 0, d = 0;
  if (ok) {
    s = noo[src_in[e]];
    d = noo[dst_in[e]];
    ok = (s >= 0) && (d >= 0);
  }
  src_out[e] = ok ? s : 0;
  dst_out[e] = ok ? d : 0;
  em_out[e] = ok ? 1 : 0;
}

// ---------------- final MLP ----------------
__global__ __launch_bounds__(256) void mlp1(const float* __restrict__ h, const float* __restrict__ W1,
    const float* __restrict__ b1, float* __restrict__ h1) {
  int o = blockIdx.x * 256 + threadIdx.x;  // 64*128
  int g = o >> 7, j = o & 127;
  const float* hp = h + g * 256;
  const float* wp = W1 + j * 256;
  float a = b1[j];
  for (int c = 0; c < 256; ++c) a += hp[c] * wp[c];
  h1[o] = fmaxf(a, 0.f);
}

__global__ __launch_bounds__(256) void mlp2(const float* __restrict__ h1, const float* __restrict__ W2,
    const float* __restrict__ b2, float* __restrict__ h2) {
  int o = blockIdx.x * 256 + threadIdx.x;  // 64*64
  int g = o >> 6, j = o & 63;
  const float* hp = h1 + g * 128;
  const float* wp = W2 + j * 128;
  float a = b2[j];
  for (int c = 0; c < 128; ++c) a += hp[c] * wp[c];
  h2[o] = fmaxf(a, 0.f);
}

__global__ __launch_bounds__(64) void mlp3(const float* __restrict__ h2, const float* __restrict__ W3,
    const float* __restrict__ b3, float* __restrict__ out) {
  int g = threadIdx.x;
  if (g >= 64) return;
  const float* hp = h2 + g * 64;
  float a = b3[0];
  for (int c = 0; c < 64; ++c) a += hp[c] * W3[c];
  out[g] = 1.f / (1.f + expf(-a));
}

extern "C" void kernel_launch(void* const* d_in, const int* in_sizes, int n_in,
                              void* d_out, int out_size, void* d_ws, size_t ws_size,
                              hipStream_t stream) {
  const int* node_ids = (const int*)d_in[0];
  const int* ei = (const int*)d_in[1];
  const float* emb = (const float*)d_in[3];
  const float* W[3][4] = {
      {(const float*)d_in[4], (const float*)d_in[5], (const float*)d_in[6], (const float*)d_in[7]},
      {(const float*)d_in[8], (const float*)d_in[9], (const float*)d_in[10], (const float*)d_in[11]},
      {(const float*)d_in[12], (const float*)d_in[13], (const float*)d_in[14], (const float*)d_in[15]}};
  const float* W1 = (const float*)d_in[16];
  const float* b1 = (const float*)d_in[17];
  const float* W2 = (const float*)d_in[18];
  const float* b2 = (const float*)d_in[19];
  const float* W3 = (const float*)d_in[20];
  const float* b3 = (const float*)d_in[21];
  float* out = (float*)d_out;

  const int E = NEDGES;
  char* ws = (char*)d_ws;
  size_t o = 0;
  auto alloc = [&](size_t bytes) { void* p = ws + o; o = (o + bytes + 255) & ~(size_t)255; return p; };
  float* X = (float*)alloc((size_t)NNODES * 128 * 4);
  float* MEAN = (float*)alloc((size_t)NNODES * 128 * 4);
  int* ES = (int*)alloc((size_t)E * 4);
  int* ED = (int*)alloc((size_t)E * 4);
  int* EM = (int*)alloc((size_t)E * 4);
  int* ESORT = (int*)alloc((size_t)E * 4);
  int* OFF = (int*)alloc((size_t)(NNODES + 1) * 4);
  int* CUR = (int*)alloc((size_t)NNODES * 4);
  int* CNT = (int*)alloc((size_t)NNODES * 4);
  int* BSUM = (int*)alloc(1024);
  float* SC = (float*)alloc((size_t)NNODES * 4);
  float* TS = (float*)alloc((size_t)NNODES * 4);
  int* PERM = (int*)alloc((size_t)NNODES * 4);
  int* NOO = (int*)alloc((size_t)NNODES * 4);
  float* PMAX = (float*)alloc((size_t)GRAPHS * RSLICES * 128 * 4);
  float* PSUM = (float*)alloc((size_t)GRAPHS * RSLICES * 128 * 4);
  float* H = (float*)alloc(64 * 256 * 4);
  float* H1 = (float*)alloc(64 * 128 * 4);
  float* H2 = (float*)alloc(64 * 64 * 4);

  embed_kernel<<<NNODES * 32 / 256, 256, 0, stream>>>(node_ids, emb, X);
  hipMemsetAsync(H, 0, 64 * 256 * 4, stream);

  struct LayerP { int n, np, k; };
  LayerP L[3] = {{131072, 2048, 1639}, {104896, 1639, 1312}, {83968, 1312, 1050}};
  const int* src = ei;
  const int* dst = ei + E;
  const int* em = nullptr;

  for (int li = 0; li < 3; ++li) {
    int n = L[li].n, np = L[li].np, k = L[li].k;
    int n_new = 64 * k;
    const float *Wl = W[li][0], *Wr = W[li][1], *bl = W[li][2], *pw = W[li][3];

    hipMemsetAsync(CNT, 0, (size_t)n * 4, stream);
    count_kernel<<<E / 256, 256, 0, stream>>>(dst, em, CNT, E);
    int nscan = n + 1, nblk = (nscan + 1023) / 1024;
    scanA<<<nblk, 1024, 0, stream>>>(CNT, OFF, BSUM, nscan, n);
    scanB<<<1, 64, 0, stream>>>(BSUM, nblk);
    scanC<<<nblk, 1024, 0, stream>>>(OFF, BSUM, CUR, nscan, n);
    fill_kernel<<<E / 256, 256, 0, stream>>>(src, dst, em, CUR, ESORT, E);
    aggregate_kernel<<<n / 4, 256, 0, stream>>>(X, OFF, ESORT, MEAN, n);
    sage_gemm<<<n / 64, 256, 0, stream>>>(X, MEAN, MEAN, Wl, Wr, bl);
    score_kernel<<<n / 4, 256, 0, stream>>>(MEAN, pw, SC, n);
    topk_kernel<<<GRAPHS, 256, 0, stream>>>(SC, np, k, TS, PERM, NOO);
    gather_kernel<<<n_new / 8, 256, 0, stream>>>(MEAN, PERM, TS, X, n_new);
    readout_part<<<GRAPHS * RSLICES, 256, 0, stream>>>(X, k, PMAX, PSUM);
    readout_comb<<<32, 256, 0, stream>>>(PMAX, PSUM, k, H);
    if (li < 2) {
      remap_kernel<<<E / 256, 256, 0, stream>>>(src, dst, em, NOO, ES, ED, EM, E);
      src = ES; dst = ED; em = EM;
    }
  }

  mlp1<<<32, 256, 0, stream>>>(H, W1, b1, H1);
  mlp2<<<16, 256, 0, stream>>>(H1, W2, b2, H2);
  mlp3<<<1, 64, 0, stream>>>(H2, W3, b3, out);
}